// Round 1
// baseline (983.971 us; speedup 1.0000x reference)
//
#include <hip/hip_runtime.h>
#include <hip/hip_bf16.h>
#include <math.h>

#define N_ATOMS 4096
#define N_EDGES 131072
#define D_NODE 64
#define D_MSG 128

__device__ __forceinline__ float silu_f(float x) {
    return x / (1.0f + __expf(-x));
}

// ---------------------------------------------------------------------------
// Edge kernel: per 64-edge tile: rbf/sh -> radial MLP -> factored TP GEMM
// (only first 64 output cols of W_tp are ever used downstream) -> atomic
// scatter into agg[dst][0:64].
// ---------------------------------------------------------------------------
__global__ __launch_bounds__(256, 2) void edge_kernel(
    const float* __restrict__ evec, const float* __restrict__ elen,
    const int* __restrict__ eidx,
    const float* __restrict__ Wr1, const float* __restrict__ br1,
    const float* __restrict__ Wr2, const float* __restrict__ br2,
    const float* __restrict__ Wtp, const float* __restrict__ btp,
    float* __restrict__ agg)
{
    __shared__ __align__(16) float shT[9][64];    // sh_T[s][e]
    __shared__ __align__(16) float RT[128][64];   // radial2 transposed [c][e]
    __shared__ __align__(16) float buf[128 * 64]; // rbfT[8][64] + R1T[64][64], later Wt[128][64]
    float* rbfT = buf;            // [8][64]
    float* R1T  = buf + 8 * 64;   // [64][64]
    float* Wt   = buf;            // [128][64] (after radial stages complete)

    const int t  = threadIdx.x;
    const int E0 = blockIdx.x * 64;
    const float PI6 = 0.52359877559829887308f; // pi/6

    // ---- stage 1: per-edge scalars (64 threads) ----
    if (t < 64) {
        int e = E0 + t;
        float vx = evec[e * 3 + 0], vy = evec[e * 3 + 1], vz = evec[e * 3 + 2];
        float r = sqrtf(vx * vx + vy * vy + vz * vz) + 1e-8f;
        float inv = 1.0f / r;
        float x = vx * inv, y = vy * inv, z = vz * inv;
        shT[0][t] = 1.0f;
        shT[1][t] = y;
        shT[2][t] = z;
        shT[3][t] = x;
        shT[4][t] = 3.0f * z * z - 1.0f;
        shT[5][t] = x * z;
        shT[6][t] = y * z;
        shT[7][t] = x * y;
        shT[8][t] = x * x - y * y;
        float len = elen[e];
        float env = 0.5f * (cosf(len * PI6) + 1.0f) * (len < 6.0f ? 1.0f : 0.0f);
        float invl = env / len;
        #pragma unroll
        for (int f = 0; f < 8; ++f)
            rbfT[f * 64 + t] = sinf(len * ((float)(f + 1) * PI6)) * invl;
    }
    __syncthreads();

    // ---- stage 2: radial1[64] = silu(rbf @ W_r1 + b_r1) ----
    {
        int e = t & 63, g = t >> 6;
        float rb[8];
        #pragma unroll
        for (int f = 0; f < 8; ++f) rb[f] = rbfT[f * 64 + e];
        #pragma unroll
        for (int i = 0; i < 16; ++i) {
            int ko = g * 16 + i;
            float acc = br1[ko];
            #pragma unroll
            for (int f = 0; f < 8; ++f) acc = fmaf(rb[f], Wr1[f * 64 + ko], acc);
            R1T[ko * 64 + e] = silu_f(acc);
        }
    }
    __syncthreads();

    // ---- stage 3: radial2[128] = silu(radial1 @ W_r2 + b_r2) -> RT[c][e] ----
    {
        int e = t & 63, g = t >> 6;
        int c0 = g * 32;
        float acc[32];
        #pragma unroll
        for (int j = 0; j < 32; ++j) acc[j] = br2[c0 + j];
        for (int k = 0; k < 64; ++k) {
            float rv = R1T[k * 64 + e];
            #pragma unroll
            for (int j = 0; j < 32; ++j)
                acc[j] = fmaf(rv, Wr2[k * 128 + c0 + j], acc[j]);
        }
        #pragma unroll
        for (int j = 0; j < 32; ++j) RT[c0 + j][e] = silu_f(acc[j]);
    }
    __syncthreads();

    // ---- phase B: C[64e][64o] = sum_s sh_s * (R @ Ws),  Ws = gathered W_tp ----
    const int e0 = (t & 15) * 4;
    const int o0 = (t >> 4) * 4;
    float acc[4][4] = {};
    for (int s = 0; s < 9; ++s) {
        for (int idx = t; idx < 128 * 64; idx += 256) {
            int c = idx >> 6, o = idx & 63;
            int row = (s == 0) ? c : (s < 4 ? 128 + c * 3 + (s - 1)
                                            : 512 + c * 5 + (s - 4));
            Wt[idx] = Wtp[row * 128 + o];
        }
        __syncthreads();
        float tmp[4][4] = {};
        #pragma unroll 2
        for (int k = 0; k < 128; ++k) {
            float4 a4 = *(const float4*)&RT[k][e0];
            float4 w4 = *(const float4*)&Wt[(k << 6) + o0];
            float av[4] = {a4.x, a4.y, a4.z, a4.w};
            float wv[4] = {w4.x, w4.y, w4.z, w4.w};
            #pragma unroll
            for (int i = 0; i < 4; ++i)
                #pragma unroll
                for (int j = 0; j < 4; ++j)
                    tmp[i][j] = fmaf(av[i], wv[j], tmp[i][j]);
        }
        #pragma unroll
        for (int i = 0; i < 4; ++i) {
            float shv = shT[s][e0 + i];
            #pragma unroll
            for (int j = 0; j < 4; ++j)
                acc[i][j] = fmaf(shv, tmp[i][j], acc[i][j]);
        }
        __syncthreads();
    }

    // ---- phase C: scatter (+ b_tp) into agg[dst][0:64] ----
    #pragma unroll
    for (int i = 0; i < 4; ++i) {
        int e = E0 + e0 + i;
        int dst = eidx[N_EDGES + e];
        #pragma unroll
        for (int j = 0; j < 4; ++j)
            atomicAdd(&agg[dst * 64 + o0 + j], acc[i][j] + btp[o0 + j]);
    }
}

// ---------------------------------------------------------------------------
// combined[n] = [embed[z[n]] | agg[n][0:64]]
// ---------------------------------------------------------------------------
__global__ void combined_kernel(const int* __restrict__ an,
                                const float* __restrict__ emb,
                                const float* __restrict__ agg,
                                float* __restrict__ comb)
{
    int i = blockIdx.x * 256 + threadIdx.x;
    if (i < N_ATOMS * 64) {
        int n = i >> 6, d = i & 63;
        comb[n * 128 + d]      = emb[an[n] * 64 + d];
        comb[n * 128 + 64 + d] = agg[n * 64 + d];
    }
}

// ---------------------------------------------------------------------------
// Generic node GEMM: C[4096 x N] = act(A[4096 x 128] @ W[128 x N] + b)
// ACT: 0 = none, 1 = silu, 2 = gate epilogue (sig(pre)*aux1 + (1-sig)*aux2)
// ---------------------------------------------------------------------------
template <int ACT>
__global__ __launch_bounds__(256, 2) void gemm128(
    const float* __restrict__ A, const float* __restrict__ W,
    const float* __restrict__ bias, float* __restrict__ C, int N,
    const float* __restrict__ aux1, const float* __restrict__ aux2)
{
    __shared__ __align__(16) float AT[128][64]; // swizzled transpose of A tile
    __shared__ __align__(16) float Ws[128][64];
    const int t  = threadIdx.x;
    const int M0 = blockIdx.x * 64;
    const int N0 = blockIdx.y * 64;

    for (int idx = t; idx < 64 * 128; idx += 256) {
        int m = idx >> 7, k = idx & 127;
        AT[k][m ^ ((k & 15) << 2)] = A[(M0 + m) * 128 + k];
    }
    for (int idx = t; idx < 128 * 64; idx += 256) {
        int k = idx >> 6, o = idx & 63;
        Ws[k][o] = W[k * N + N0 + o];
    }
    __syncthreads();

    const int m0 = (t & 15) * 4;
    const int o0 = (t >> 4) * 4;
    float acc[4][4] = {};
    #pragma unroll 2
    for (int k = 0; k < 128; ++k) {
        int xs = (k & 15) << 2;
        float4 a4 = *(const float4*)&AT[k][m0 ^ xs];
        float4 w4 = *(const float4*)&Ws[k][o0];
        float av[4] = {a4.x, a4.y, a4.z, a4.w};
        float wv[4] = {w4.x, w4.y, w4.z, w4.w};
        #pragma unroll
        for (int i = 0; i < 4; ++i)
            #pragma unroll
            for (int j = 0; j < 4; ++j)
                acc[i][j] = fmaf(av[i], wv[j], acc[i][j]);
    }

    #pragma unroll
    for (int i = 0; i < 4; ++i) {
        int m = M0 + m0 + i;
        #pragma unroll
        for (int j = 0; j < 4; ++j) {
            int o = N0 + o0 + j;
            float v = acc[i][j] + bias[o];
            if (ACT == 1) v = silu_f(v);
            if (ACT == 2) {
                float sg = 1.0f / (1.0f + __expf(-v));
                v = sg * aux1[m * 128 + o] + (1.0f - sg) * aux2[m * 128 + o];
            }
            C[m * N + o] = v;
        }
    }
}

// ---------------------------------------------------------------------------
// Flash-style f32 attention: block = (head, 64-row tile), full softmax over m
// qkv layout: [n][384] = [q(128) | k(128) | v(128)], head-major within each.
// ---------------------------------------------------------------------------
__global__ __launch_bounds__(256) void attn_kernel(
    const float* __restrict__ qkv, float* __restrict__ att)
{
    __shared__ __align__(16) float QT[32][64];   // swizzled
    __shared__ __align__(16) float KT[32][64];   // swizzled
    __shared__ __align__(16) float Vs[64 * 32];
    __shared__ __align__(16) float PT[64][64];   // swizzled

    const int t  = threadIdx.x;
    const int h  = blockIdx.x >> 6;
    const int N0 = (blockIdx.x & 63) * 64;
    const float scale = 0.17677669529663687f; // 1/sqrt(32)

    for (int idx = t; idx < 64 * 32; idx += 256) {
        int n = idx >> 5, d = idx & 31;
        QT[d][n ^ ((d & 15) << 2)] = qkv[(N0 + n) * 384 + h * 32 + d] * scale;
    }

    const int n0 = (t >> 4) * 4;  // rows owned (same group in QK and PV phases)
    const int m0 = (t & 15) * 4;  // QK cols
    const int d0 = (t & 15) * 2;  // PV cols

    float run_m[4], run_l[4], O[4][2];
    #pragma unroll
    for (int i = 0; i < 4; ++i) {
        run_m[i] = -1e30f; run_l[i] = 0.0f; O[i][0] = 0.0f; O[i][1] = 0.0f;
    }

    for (int mt = 0; mt < 64; ++mt) {
        __syncthreads(); // previous PV readers done before restaging
        int Mb = mt * 64;
        for (int idx = t; idx < 64 * 32; idx += 256) {
            int m = idx >> 5, d = idx & 31;
            KT[d][m ^ ((d & 15) << 2)] = qkv[(Mb + m) * 384 + 128 + h * 32 + d];
            Vs[m * 32 + d]             = qkv[(Mb + m) * 384 + 256 + h * 32 + d];
        }
        __syncthreads();

        // QK^T tile
        float s[4][4] = {};
        #pragma unroll 2
        for (int k = 0; k < 32; ++k) {
            int xs = (k & 15) << 2;
            float4 a4 = *(const float4*)&QT[k][n0 ^ xs];
            float4 b4 = *(const float4*)&KT[k][m0 ^ xs];
            float av[4] = {a4.x, a4.y, a4.z, a4.w};
            float bv[4] = {b4.x, b4.y, b4.z, b4.w};
            #pragma unroll
            for (int i = 0; i < 4; ++i)
                #pragma unroll
                for (int j = 0; j < 4; ++j)
                    s[i][j] = fmaf(av[i], bv[j], s[i][j]);
        }

        // online softmax (rows replicated across the 16-lane group)
        #pragma unroll
        for (int i = 0; i < 4; ++i) {
            float tm = fmaxf(fmaxf(s[i][0], s[i][1]), fmaxf(s[i][2], s[i][3]));
            tm = fmaxf(tm, __shfl_xor(tm, 1, 16));
            tm = fmaxf(tm, __shfl_xor(tm, 2, 16));
            tm = fmaxf(tm, __shfl_xor(tm, 4, 16));
            tm = fmaxf(tm, __shfl_xor(tm, 8, 16));
            float nm = fmaxf(run_m[i], tm);
            float c  = __expf(run_m[i] - nm);
            run_m[i] = nm;
            float rs = 0.0f;
            #pragma unroll
            for (int j = 0; j < 4; ++j) {
                s[i][j] = __expf(s[i][j] - nm);
                rs += s[i][j];
            }
            rs += __shfl_xor(rs, 1, 16);
            rs += __shfl_xor(rs, 2, 16);
            rs += __shfl_xor(rs, 4, 16);
            rs += __shfl_xor(rs, 8, 16);
            run_l[i] = run_l[i] * c + rs;
            O[i][0] *= c; O[i][1] *= c;
            #pragma unroll
            for (int j = 0; j < 4; ++j) {
                int m = m0 + j;
                PT[m][(n0 + i) ^ ((m & 15) << 2)] = s[i][j];
            }
        }
        __syncthreads();

        // PV: O[n][d] += sum_m P[n][m] * V[m][d]
        #pragma unroll 2
        for (int m = 0; m < 64; ++m) {
            float4 p4 = *(const float4*)&PT[m][n0 ^ ((m & 15) << 2)];
            float2 v2 = *(const float2*)&Vs[m * 32 + d0];
            float pv[4] = {p4.x, p4.y, p4.z, p4.w};
            #pragma unroll
            for (int i = 0; i < 4; ++i) {
                O[i][0] = fmaf(pv[i], v2.x, O[i][0]);
                O[i][1] = fmaf(pv[i], v2.y, O[i][1]);
            }
        }
    }

    #pragma unroll
    for (int i = 0; i < 4; ++i) {
        float invl = 1.0f / run_l[i];
        float2 o2 = make_float2(O[i][0] * invl, O[i][1] * invl);
        *(float2*)&att[(N0 + n0 + i) * 128 + h * 32 + d0] = o2;
    }
}

// ---------------------------------------------------------------------------
extern "C" void kernel_launch(void* const* d_in, const int* in_sizes, int n_in,
                              void* d_out, int out_size, void* d_ws, size_t ws_size,
                              hipStream_t stream) {
    const int*   an    = (const int*)d_in[0];
    const int*   eidx  = (const int*)d_in[2];
    const float* evec  = (const float*)d_in[3];
    const float* elen  = (const float*)d_in[4];
    const float* emb   = (const float*)d_in[5];
    const float* Wr1   = (const float*)d_in[6];
    const float* br1   = (const float*)d_in[7];
    const float* Wr2   = (const float*)d_in[8];
    const float* br2   = (const float*)d_in[9];
    const float* Wtp   = (const float*)d_in[10];
    const float* btp   = (const float*)d_in[11];
    const float* Wm1   = (const float*)d_in[12];
    const float* bm1   = (const float*)d_in[13];
    const float* Wm2   = (const float*)d_in[14];
    const float* bm2   = (const float*)d_in[15];
    const float* Wqkv  = (const float*)d_in[16];
    const float* bqkv  = (const float*)d_in[17];
    const float* Wao   = (const float*)d_in[18];
    const float* bao   = (const float*)d_in[19];
    const float* Wg    = (const float*)d_in[20];
    const float* bg    = (const float*)d_in[21];
    const float* Wo    = (const float*)d_in[22];
    const float* bo    = (const float*)d_in[23];

    float* ws    = (float*)d_ws;
    float* agg   = ws;                       // 4096*64
    float* comb  = agg  + N_ATOMS * 64;      // 4096*128
    float* h1    = comb + N_ATOMS * 128;     // 4096*128
    float* upd   = h1   + N_ATOMS * 128;     // 4096*128
    float* qkvb  = upd  + N_ATOMS * 128;     // 4096*384
    float* attd  = qkvb + N_ATOMS * 384;     // 4096*128
    float* aob   = attd + N_ATOMS * 128;     // 4096*128
    float* outp  = h1;                       // reuse (h1 dead by then)

    hipMemsetAsync(agg, 0, N_ATOMS * 64 * sizeof(float), stream);

    edge_kernel<<<N_EDGES / 64, 256, 0, stream>>>(
        evec, elen, eidx, Wr1, br1, Wr2, br2, Wtp, btp, agg);

    combined_kernel<<<(N_ATOMS * 64) / 256, 256, 0, stream>>>(an, emb, agg, comb);

    gemm128<1><<<dim3(64, 2), 256, 0, stream>>>(comb, Wm1, bm1, h1, 128, nullptr, nullptr);
    gemm128<0><<<dim3(64, 2), 256, 0, stream>>>(h1, Wm2, bm2, upd, 128, nullptr, nullptr);
    gemm128<0><<<dim3(64, 6), 256, 0, stream>>>(upd, Wqkv, bqkv, qkvb, 384, nullptr, nullptr);

    attn_kernel<<<256, 256, 0, stream>>>(qkvb, attd);

    gemm128<0><<<dim3(64, 2), 256, 0, stream>>>(attd, Wao, bao, aob, 128, nullptr, nullptr);
    gemm128<2><<<dim3(64, 2), 256, 0, stream>>>(upd, Wg, bg, outp, 128, aob, upd);
    gemm128<0><<<dim3(64, 2), 256, 0, stream>>>(outp, Wo, bo, (float*)d_out, 128, nullptr, nullptr);
}